// Round 9
// baseline (52.815 us; speedup 1.0000x reference)
//
#include <hip/hip_runtime.h>

// Segmented histogram: out[g, c] = sum of w[i] for i in [ptr[g], ptr[g+1])
// with x[i] == c < out_dim.
//
// Rounds 1-8: seven structures, all ~50-60us, all CU-side counters idle, and
// byte-rate invariant at ~1 TB/s with FETCH pinned at exactly half the 64MB
// read stream. Model: fabric serves ~1 TB/s in this small-kernel regime; the
// per-XCD read footprint (8MB) is 2x the 4MB L2, so replays hit L2 for half
// the reads. This round tests the model's two levers on the round-8 structure:
//   - nontemporal row stores: keep out's 16MB out of L2, freeing it for reads
//   - bijective XCD-chunked block swizzle: each XCD reads one contiguous,
//     replay-stable 8MB region (T1)
// If FETCH/dur don't move, the ~1 TB/s state is the environment floor.

#define ODIM 256

extern "C" __global__ __launch_bounds__(256, 8)
void wave_hist_kernel(const int* __restrict__ x, const int* __restrict__ ptr,
                      const float* __restrict__ w, float* __restrict__ out,
                      int num_graphs, int nblocks) {
    __shared__ float hist[4][ODIM];

    const int wv   = (int)threadIdx.x >> 6;
    const int lane = (int)threadIdx.x & 63;
    float* h = hist[wv];

    // bijective XCD-chunked swizzle (nblocks % 8 == 0 guaranteed by host):
    // XCD k owns contiguous blocks [k*nblocks/8, (k+1)*nblocks/8)
    const int b   = (int)blockIdx.x;
    const int blk = (b & 7) * (nblocks >> 3) + (b >> 3);

    const int total_waves = nblocks * 4;

    for (int g = blk * 4 + wv; g < num_graphs; g += total_waves) {
        const int s = ptr[g];
        const int e = ptr[g + 1];

        // zero private hist (wave-private: no barrier; in-order DS ops)
        #pragma unroll
        for (int k = 0; k < 4; ++k) h[lane + (k << 6)] = 0.0f;

        // alignment split: head [s,a0) | body [a0,a1) 16B-aligned | tail [a1,e)
        const int a0 = min((s + 3) & ~3, e);
        const int a1 = max(e & ~3, a0);

        // head (<=3 nodes)
        {
            const int i = s + lane;
            if (i < a0) {
                const int lbl = x[i];
                if ((unsigned)lbl < (unsigned)ODIM) atomicAdd(&h[lbl], w[i]);
            }
        }

        // body: 4 nodes/lane/iter, coalesced dwordx4
        for (int i = a0 + lane * 4; i < a1; i += 64 * 4) {
            const int4   l4 = *reinterpret_cast<const int4*>(x + i);
            const float4 w4 = *reinterpret_cast<const float4*>(w + i);
            if ((unsigned)l4.x < (unsigned)ODIM) atomicAdd(&h[l4.x], w4.x);
            if ((unsigned)l4.y < (unsigned)ODIM) atomicAdd(&h[l4.y], w4.y);
            if ((unsigned)l4.z < (unsigned)ODIM) atomicAdd(&h[l4.z], w4.z);
            if ((unsigned)l4.w < (unsigned)ODIM) atomicAdd(&h[l4.w], w4.w);
        }

        // tail (<=3 nodes)
        {
            const int i = a1 + lane;
            if (i < e) {
                const int lbl = x[i];
                if ((unsigned)lbl < (unsigned)ODIM) atomicAdd(&h[lbl], w[i]);
            }
        }

        // exclusive row store, nontemporal (bypass L2 -> keep L2 for reads)
        float* row = out + (size_t)g * ODIM;
        #pragma unroll
        for (int k = 0; k < 4; ++k) {
            __builtin_nontemporal_store(h[lane + (k << 6)], &row[lane + (k << 6)]);
        }
    }
}

// Generic fallback for out_dim != 256 (round-1 structure).
extern "C" __global__ __launch_bounds__(256)
void seg_hist_fallback(const int* __restrict__ x, const int* __restrict__ ptr,
                       const float* __restrict__ w, float* __restrict__ out,
                       int out_dim) {
    extern __shared__ float fhist[];
    const int g = blockIdx.x;
    const int start = ptr[g];
    const int end = ptr[g + 1];
    for (int c = (int)threadIdx.x; c < out_dim; c += 256) fhist[c] = 0.0f;
    __syncthreads();
    for (int i = start + (int)threadIdx.x; i < end; i += 256) {
        const int lbl = x[i];
        if ((unsigned)lbl < (unsigned)out_dim) atomicAdd(&fhist[lbl], w[i]);
    }
    __syncthreads();
    float* o = out + (size_t)g * (size_t)out_dim;
    for (int c = (int)threadIdx.x; c < out_dim; c += 256) o[c] = fhist[c];
}

extern "C" void kernel_launch(void* const* d_in, const int* in_sizes, int n_in,
                              void* d_out, int out_size, void* d_ws, size_t ws_size,
                              hipStream_t stream) {
    const int* x   = (const int*)d_in[0];
    const int* ptr = (const int*)d_in[1];
    const float* w = (const float*)d_in[2];
    float* out     = (float*)d_out;

    const int num_graphs = in_sizes[1] - 1;
    const int out_dim    = out_size / num_graphs;

    if (out_dim != ODIM) {
        seg_hist_fallback<<<num_graphs, 256, (size_t)out_dim * sizeof(float), stream>>>(
            x, ptr, w, out, out_dim);
        return;
    }

    // one wave per graph; 4 waves per block; round block count to a multiple
    // of 8 so the XCD swizzle is bijective (grid-stride covers any remainder)
    int n_blocks = (num_graphs + 3) / 4;
    n_blocks = (n_blocks + 7) & ~7;
    wave_hist_kernel<<<n_blocks, 256, 0, stream>>>(x, ptr, w, out,
                                                   num_graphs, n_blocks);
}